// Round 2
// baseline (867.980 us; speedup 1.0000x reference)
//
#include <hip/hip_runtime.h>
#include <hip/hip_bf16.h>
#include <cstdint>

// GaussMemoryStep: everything reduced to bf16 MFMA GEMMs.
// F[n,j<256]=cos(2pi(j+1)n/V), F[n,256+j]=-sin(2pi(j+1)n/V);  irfft == @ (2/V)F^T.

typedef unsigned short u16;
typedef short short8 __attribute__((ext_vector_type(8)));
typedef float f32x4 __attribute__((ext_vector_type(4)));
typedef float f4 __attribute__((ext_vector_type(4)));

__device__ __forceinline__ u16 f2bf(float f) {
  union { float f; unsigned u; } v; v.f = f;
  unsigned u = v.u;
  u += 0x7fffu + ((u >> 16) & 1u);   // round-to-nearest-even
  return (u16)(u >> 16);
}

__device__ __forceinline__ void gload_lds16(const void* g, void* l) {
  __builtin_amdgcn_global_load_lds(
      (const __attribute__((address_space(1))) void*)g,
      (__attribute__((address_space(3))) void*)l, 16, 0, 0);
}

// C[m,n] = sum_k A[m,k] * B[n,k]   (B given transposed, [N][K] row-major)
// M,N multiples of 128; K multiple of 32. 256 threads, 4 waves, 128x128 tile.
// EPI: 0 = bf16 C *= alpha; 2 = bf16 C written transposed into Vt[b][n][t];
//      3 = decay-weight epilogue (scores), bf16; 4 = fp32 out * (*scal).
template<int EPI, bool AF32>
__global__ __launch_bounds__(256, 2)
void gemm_bt(const void* __restrict__ Av, const u16* __restrict__ B,
             void* __restrict__ Cv, int M, int N, int K,
             long sA, long sB, long sC,
             const float* __restrict__ scal, float alpha)
{
  __shared__ u16 As[128 * 32] __attribute__((aligned(16)));
  __shared__ u16 Bs[128 * 32] __attribute__((aligned(16)));

  const int tid  = threadIdx.x;
  const int wave = tid >> 6, lane = tid & 63;
  const int quad = lane >> 4, l15 = lane & 15;
  const int wm = wave >> 1, wn = wave & 1;
  const int m0 = blockIdx.y * 128, n0 = blockIdx.x * 128;
  const int z  = blockIdx.z;

  const u16*   Ab = (const u16*)Av + (size_t)z * sA;
  const float* Af = (const float*)Av + (size_t)z * sA;
  const u16*   Bb = B + (size_t)z * sB;

  f32x4 acc[4][4] = {};

  // global_load_lds staging geometry (LDS linear, lane*16B)
  const int loff0 = wave * 2048 + lane * 16;
  const int loff1 = loff0 + 1024;
  const int row0s = loff0 >> 6, kof0 = (loff0 & 63) >> 1;
  const int row1s = loff1 >> 6, kof1 = (loff1 & 63) >> 1;

  for (int k0 = 0; k0 < K; k0 += 32) {
    __syncthreads();
    if (AF32) {
      const int row = tid >> 1, half = tid & 1;
      const float* ar = Af + (size_t)(m0 + row) * K + k0 + half * 16;
      f4 p0 = *(const f4*)(ar);
      f4 p1 = *(const f4*)(ar + 4);
      f4 p2 = *(const f4*)(ar + 8);
      f4 p3 = *(const f4*)(ar + 12);
      union { u16 h[16]; uint4 q[2]; } pk;
      #pragma unroll
      for (int e = 0; e < 4; ++e) {
        pk.h[e]      = f2bf(p0[e]);
        pk.h[4 + e]  = f2bf(p1[e]);
        pk.h[8 + e]  = f2bf(p2[e]);
        pk.h[12 + e] = f2bf(p3[e]);
      }
      uint4* dst = (uint4*)&As[row * 32 + half * 16];
      dst[0] = pk.q[0]; dst[1] = pk.q[1];
    } else {
      gload_lds16(Ab + (size_t)(m0 + row0s) * K + k0 + kof0, (char*)As + loff0);
      gload_lds16(Ab + (size_t)(m0 + row1s) * K + k0 + kof1, (char*)As + loff1);
    }
    gload_lds16(Bb + (size_t)(n0 + row0s) * K + k0 + kof0, (char*)Bs + loff0);
    gload_lds16(Bb + (size_t)(n0 + row1s) * K + k0 + kof1, (char*)Bs + loff1);
    __syncthreads();

    short8 a[4], b[4];
    #pragma unroll
    for (int i = 0; i < 4; ++i)
      a[i] = *(const short8*)&As[(wm * 64 + i * 16 + l15) * 32 + quad * 8];
    #pragma unroll
    for (int j = 0; j < 4; ++j)
      b[j] = *(const short8*)&Bs[(wn * 64 + j * 16 + l15) * 32 + quad * 8];
    #pragma unroll
    for (int i = 0; i < 4; ++i)
      #pragma unroll
      for (int j = 0; j < 4; ++j)
        acc[i][j] = __builtin_amdgcn_mfma_f32_16x16x32_bf16(a[i], b[j], acc[i][j], 0, 0, 0);
  }

  float dec_l2 = 0.f, oscale = 1.f;
  if (EPI == 3) {
    float logit = *scal;
    float dec = 1.f / (1.f + expf(-logit));
    dec_l2 = log2f(dec);
  }
  if (EPI == 4) oscale = *scal;

  #pragma unroll
  for (int i = 0; i < 4; ++i) {
    #pragma unroll
    for (int j = 0; j < 4; ++j) {
      f32x4 v = acc[i][j];
      const int rb = m0 + wm * 64 + i * 16 + quad * 4;
      const int cc = n0 + wn * 64 + j * 16 + l15;
      if (EPI == 0) {
        u16* C = (u16*)Cv + (size_t)z * sC;
        #pragma unroll
        for (int r = 0; r < 4; ++r)
          C[(size_t)(rb + r) * N + cc] = f2bf(v[r] * alpha);
      } else if (EPI == 2) {
        // write transposed: Vt[b][cc][t],  t = rb&2047, b = rb>>11, ld 2048
        u16* C = (u16*)Cv;
        const int bb = rb >> 11, ml = rb & 2047;
        union { u16 h[4]; uint2 q; } pk;
        #pragma unroll
        for (int r = 0; r < 4; ++r) pk.h[r] = f2bf(v[r]);
        *(uint2*)&C[((size_t)(bb << 8) + cc) * 2048 + ml] = pk.q;
      } else if (EPI == 3) {
        u16* C = (u16*)Cv + (size_t)z * sC;
        #pragma unroll
        for (int r = 0; r < 4; ++r) {
          const int d = cc - (rb + r);            // s - t
          float w = (d > 0) ? exp2f(dec_l2 * (float)(d - 1)) : 0.f;
          C[(size_t)(rb + r) * N + cc] = f2bf(v[r] * w);
        }
      } else if (EPI == 4) {
        float* C = (float*)Cv;
        #pragma unroll
        for (int r = 0; r < 4; ++r)
          C[(size_t)(rb + r) * N + cc] = v[r] * oscale;
      }
    }
  }
}

// F tables: exact integer phase reduction (n*k mod 8192) before trig.
__global__ void genF_row(u16* Fm) {           // Fm [8192][512], coalesced in j
  int idx = blockIdx.x * 256 + threadIdx.x;
  int n = idx >> 9, j = idx & 511;
  int k = (j & 255) + 1;
  int ph = (n * k) & 8191;
  float ang = (float)ph * 7.66990393942820795e-4f;  // 2*pi/8192
  float s, c; sincosf(ang, &s, &c);
  Fm[idx] = f2bf(j < 256 ? c : -s);
}
__global__ void genF_col(u16* Ft) {           // Ft [512][8192], coalesced in n
  int idx = blockIdx.x * 256 + threadIdx.x;
  int j = idx >> 13, n = idx & 8191;
  int k = (j & 255) + 1;
  int ph = (n * k) & 8191;
  float ang = (float)ph * 7.66990393942820795e-4f;
  float s, c; sincosf(ang, &s, &c);
  Ft[idx] = f2bf(j < 256 ? c : -s);
}

__global__ void cast_w4(const float* a, const float* b, const float* c, const float* d,
                        u16* oa, u16* ob, u16* oc, u16* od) {
  int i = blockIdx.x * 256 + threadIdx.x;     // 131072 each
  oa[i] = f2bf(a[i]); ob[i] = f2bf(b[i]); oc[i] = f2bf(c[i]); od[i] = f2bf(d[i]);
}

extern "C" void kernel_launch(void* const* d_in, const int* in_sizes, int n_in,
                              void* d_out, int out_size, void* d_ws, size_t ws_size,
                              hipStream_t stream)
{
  const float* x  = (const float*)d_in[0];
  const float* qw = (const float*)d_in[1];
  const float* kw = (const float*)d_in[2];
  const float* vw = (const float*)d_in[3];
  const float* ow = (const float*)d_in[4];
  const float* dl = (const float*)d_in[5];   // decay_logit
  const float* os = (const float*)d_in[6];   // out_scale
  float* out = (float*)d_out;

  char* W = (char*)d_ws;
  const size_t MB = 1024 * 1024;
  u16* Fm  = (u16*)(W);             // [8192][512]   8 MB
  u16* Ft  = (u16*)(W + 8 * MB);    // [512][8192]   8 MB
  u16* Xri = (u16*)(W + 16 * MB);   // [8192][512]   8 MB
  u16* Qb  = (u16*)(W + 24 * MB);   // [8192][256]   4 MB
  u16* Kb  = (u16*)(W + 28 * MB);   // [8192][256]   4 MB
  u16* Vt  = (u16*)(W + 32 * MB);   // [4][256][2048] 4 MB
  u16* Wot = (u16*)(W + 36 * MB);   // [8192][256]   4 MB
  u16* S   = (u16*)(W + 40 * MB);   // [4][2048][2048] 32 MB
  u16* R   = (u16*)(W + 72 * MB);   // [8192][256]   4 MB
  u16* qwb = (u16*)(W + 76 * MB);   // 4 x 256 KB
  u16* kwb = qwb + 131072;
  u16* vwb = kwb + 131072;
  u16* owb = vwb + 131072;

  genF_row<<<8192 * 512 / 256, 256, 0, stream>>>(Fm);
  genF_col<<<8192 * 512 / 256, 256, 0, stream>>>(Ft);
  cast_w4<<<131072 / 256, 256, 0, stream>>>(qw, kw, vw, ow, qwb, kwb, vwb, owb);

  // G1: Xri = x @ F           M=8192 N=512 K=8192  (A is fp32)
  gemm_bt<0, true ><<<dim3(4, 64, 1), 256, 0, stream>>>(x, Ft, Xri, 8192, 512, 8192, 0, 0, 0, nullptr, 1.f);
  // G2: q, k, v = Xri @ w^T   M=8192 N=256 K=512   (v written transposed)
  gemm_bt<0, false><<<dim3(2, 64, 1), 256, 0, stream>>>(Xri, qwb, Qb, 8192, 256, 512, 0, 0, 0, nullptr, 1.f);
  gemm_bt<0, false><<<dim3(2, 64, 1), 256, 0, stream>>>(Xri, kwb, Kb, 8192, 256, 512, 0, 0, 0, nullptr, 1.f);
  gemm_bt<2, false><<<dim3(2, 64, 1), 256, 0, stream>>>(Xri, vwb, Vt, 8192, 256, 512, 0, 0, 0, nullptr, 1.f);
  // G3: Wot = (2/V) * F @ o_w^T   M=8192 N=256 K=512
  gemm_bt<0, false><<<dim3(2, 64, 1), 256, 0, stream>>>(Fm, owb, Wot, 8192, 256, 512, 0, 0, 0, nullptr, 2.f / 8192.f);
  // G4: S[b] = (q k^T) .* weight   M=N=2048 K=256, z=batch
  gemm_bt<3, false><<<dim3(16, 16, 4), 256, 0, stream>>>(Qb, Kb, S, 2048, 2048, 256,
                                                         2048L * 256, 2048L * 256, 2048L * 2048, dl, 1.f);
  // G5: R[b] = S[b] @ v[b]    M=2048 N=256 K=2048
  gemm_bt<0, false><<<dim3(2, 16, 4), 256, 0, stream>>>(S, Vt, R, 2048, 256, 2048,
                                                        2048L * 2048, 256L * 2048, 2048L * 256, nullptr, 1.f);
  // G6: out = (R @ Wot^T) * out_scale   M=8192 N=8192 K=256, fp32 out
  gemm_bt<4, false><<<dim3(64, 64, 1), 256, 0, stream>>>(R, Wot, out, 8192, 8192, 256, 0, 0, 0, os, 1.f);
}